// Round 2
// baseline (461.079 us; speedup 1.0000x reference)
//
#include <hip/hip_runtime.h>
#include <math.h>

#define T_STEPS 32
#define NB 64      // batch
#define CC 512     // channels
#define AA 32      // cc_acc size

__device__ __forceinline__ float sig_decay(const float* wp) {
    // decay = 1 - sigmoid(w)
    return 1.0f - 1.0f / (1.0f + expf(-wp[0]));
}

// ---------------------------------------------------------------------------
// Front end: transpose + synapse(tau=2) + jeffress(2->32) + LIF(1.5) +
// synapse(sf0) + w_cc(32->1) + IF + synapse(sf1).  One thread per (n,c),
// loops t; all recurrent state in registers.  Writes y7 (T*N, 512).
// ---------------------------------------------------------------------------
__global__ __launch_bounds__(256) void front_kernel(
    const float* __restrict__ x, const float* __restrict__ w_jeff,
    const float* __restrict__ w_cc, const float* __restrict__ w_sf0,
    const float* __restrict__ w_sf1, float* __restrict__ y7)
{
    __shared__ float wj[2 * AA];
    __shared__ float wcc[AA];
    int tid = threadIdx.x;
    if (tid < 2 * AA) wj[tid] = w_jeff[tid];
    if (tid < AA) wcc[tid] = w_cc[tid];
    __syncthreads();

    int g = blockIdx.x * 256 + tid;     // n*CC + c
    int n = g >> 9;
    int c = g & (CC - 1);

    const float inv_lif = 1.0f / 1.5f;
    float d0 = sig_decay(w_sf0);
    float d1 = sig_decay(w_sf1);

    float s0 = 0.f, s1 = 0.f, v6 = 0.f, u1 = 0.f;
    float v[AA], u[AA];
#pragma unroll
    for (int a = 0; a < AA; a++) { v[a] = 0.f; u[a] = 0.f; }

    for (int t = 0; t < T_STEPS; t++) {
        const float* xp = x + (size_t)((t * NB + n) * 2) * CC + c;
        s0 = s0 * 0.5f + xp[0];     // synapse filter, tau=2 (decay 0.5)
        s1 = s1 * 0.5f + xp[CC];
        float acc = 0.f;
#pragma unroll
        for (int a = 0; a < AA; a++) {
            float z  = wj[2 * a] * s0 + wj[2 * a + 1] * s1;
            float vv = v[a] + (z - v[a]) * inv_lif;   // LIF decay_input
            bool  sp = vv >= 1.0f;
            v[a] = sp ? 0.0f : vv;                    // hard reset
            float uu = u[a] * d0 + (sp ? 1.0f : 0.0f);
            u[a] = uu;
            acc += wcc[a] * uu;
        }
        v6 += acc;                                    // IFNode
        bool sp6 = v6 >= 1.0f;
        v6 = sp6 ? 0.0f : v6;
        u1 = u1 * d1 + (sp6 ? 1.0f : 0.0f);           // sf1 filter
        y7[(size_t)(t * NB + n) * CC + c] = u1;
    }
}

// ---------------------------------------------------------------------------
// IF (+ optional synapse filter) over the (deterministic, in-order) sum of
// `nparts` split-K partial buffers.  Result written in place into part 0.
// One thread per (n,f), loop t.  w_sf == nullptr -> emit raw spikes.
// ---------------------------------------------------------------------------
__global__ __launch_bounds__(256) void if_filter_kernel(
    float* __restrict__ buf, size_t partStride, int nparts,
    const float* __restrict__ w_sf, int F)
{
    int tid = blockIdx.x * 256 + threadIdx.x;   // n*F + f
    const int NF = NB * F;
    bool  filt = (w_sf != nullptr);
    float d = filt ? sig_decay(w_sf) : 0.0f;
    float v = 0.f, u = 0.f;
    for (int t = 0; t < T_STEPS; t++) {
        size_t off = (size_t)t * NF + tid;
        float zt = buf[off];
        for (int p = 1; p < nparts; p++) zt += buf[p * partStride + off];
        v += zt;
        bool sp = v >= 1.0f;
        v = sp ? 0.0f : v;
        float s = sp ? 1.0f : 0.0f;
        if (filt) { u = u * d + s; buf[off] = u; }
        else      { buf[off] = s; }
    }
}

// ---------------------------------------------------------------------------
// C = A * B^T, split-K.  A: (M,K) row-major, B: (N,K) row-major.
// Partial for split s goes to C + s*M*N over K range [s*K_per, (s+1)*K_per).
// 256 threads as 16x16, micro-tile 8x4 (BM=128, BN=64), BK=16,
// double-buffered LDS with register prefetch of the next K-tile.
// ---------------------------------------------------------------------------
template <int BM, int BN, int BK>
__global__ __launch_bounds__(256) void gemm_nt_db(
    const float* __restrict__ A, const float* __restrict__ B,
    float* __restrict__ C, int M, int N, int K_total, int K_per)
{
    constexpr int TM = 8;
    constexpr int TN = 4;
    constexpr int A_L = BM * BK / (256 * 4);   // float4 loads per thread (A)
    constexpr int B_L = BN * BK / (256 * 4);   // float4 loads per thread (B)

    __shared__ float As[2][BK][BM + 4];
    __shared__ float Bs[2][BK][BN + 4];

    const int tid = threadIdx.x;
    const int tx  = tid & 15;        // col group (TN each)
    const int ty  = tid >> 4;        // row group (TM each)
    const int bm  = blockIdx.y * BM;
    const int bn  = blockIdx.x * BN;
    const int s   = blockIdx.z;
    const int kbeg = s * K_per;

    float4 aReg[A_L], bReg[B_L];

    auto load_regs = [&](int k0) {
#pragma unroll
        for (int i = 0; i < A_L; i++) {
            int idx = i * 256 + tid;
            int row = idx >> 2;
            int kq  = idx & 3;
            aReg[i] = *(const float4*)(A + (size_t)(bm + row) * K_total + k0 + kq * 4);
        }
#pragma unroll
        for (int i = 0; i < B_L; i++) {
            int idx = i * 256 + tid;
            int row = idx >> 2;
            int kq  = idx & 3;
            bReg[i] = *(const float4*)(B + (size_t)(bn + row) * K_total + k0 + kq * 4);
        }
    };
    auto store_lds = [&](int buf) {
#pragma unroll
        for (int i = 0; i < A_L; i++) {
            int idx = i * 256 + tid;
            int row = idx >> 2;
            int kq  = idx & 3;
            As[buf][kq * 4 + 0][row] = aReg[i].x;
            As[buf][kq * 4 + 1][row] = aReg[i].y;
            As[buf][kq * 4 + 2][row] = aReg[i].z;
            As[buf][kq * 4 + 3][row] = aReg[i].w;
        }
#pragma unroll
        for (int i = 0; i < B_L; i++) {
            int idx = i * 256 + tid;
            int row = idx >> 2;
            int kq  = idx & 3;
            Bs[buf][kq * 4 + 0][row] = bReg[i].x;
            Bs[buf][kq * 4 + 1][row] = bReg[i].y;
            Bs[buf][kq * 4 + 2][row] = bReg[i].z;
            Bs[buf][kq * 4 + 3][row] = bReg[i].w;
        }
    };

    float acc[TM][TN];
#pragma unroll
    for (int i = 0; i < TM; i++)
#pragma unroll
        for (int j = 0; j < TN; j++) acc[i][j] = 0.f;

    load_regs(kbeg);
    store_lds(0);
    __syncthreads();

    const int nk = K_per / BK;
    for (int kt = 0; kt < nk; kt++) {
        int cur = kt & 1;
        bool has_next = (kt + 1 < nk);
        if (has_next) load_regs(kbeg + (kt + 1) * BK);   // prefetch to regs
#pragma unroll
        for (int kk = 0; kk < BK; kk++) {
            float4 a0 = *(const float4*)&As[cur][kk][ty * TM];
            float4 a1 = *(const float4*)&As[cur][kk][ty * TM + 4];
            float4 b0 = *(const float4*)&Bs[cur][kk][tx * TN];
            float ar[TM] = {a0.x, a0.y, a0.z, a0.w, a1.x, a1.y, a1.z, a1.w};
            float br[TN] = {b0.x, b0.y, b0.z, b0.w};
#pragma unroll
            for (int i = 0; i < TM; i++)
#pragma unroll
                for (int j = 0; j < TN; j++) acc[i][j] += ar[i] * br[j];
        }
        if (has_next) store_lds(cur ^ 1);                // LDS write after compute
        __syncthreads();
    }

    float* Cp = C + (size_t)s * M * N;
#pragma unroll
    for (int i = 0; i < TM; i++) {
        float4 o;
        o.x = acc[i][0]; o.y = acc[i][1]; o.z = acc[i][2]; o.w = acc[i][3];
        *(float4*)(Cp + (size_t)(bm + ty * TM + i) * N + bn + tx * TN) = o;
    }
}

// ---------------------------------------------------------------------------
// Final: out[t,n] = cumsum_t( dot(y15[t,n,:512], W_out) + b ).
// One wave (64 threads) per n.
// ---------------------------------------------------------------------------
__global__ __launch_bounds__(64) void final_kernel(
    const float* __restrict__ y15, const float* __restrict__ W_out,
    const float* __restrict__ b_out, float* __restrict__ out)
{
    int n = blockIdx.x;
    int lane = threadIdx.x;
    float w[8];
#pragma unroll
    for (int j = 0; j < 8; j++) w[j] = W_out[lane + j * 64];
    float b = b_out[0];
    float cum = 0.f;
    for (int t = 0; t < T_STEPS; t++) {
        const float* yp = y15 + (size_t)(t * NB + n) * 512;
        float p = 0.f;
#pragma unroll
        for (int j = 0; j < 8; j++) p += yp[lane + j * 64] * w[j];
#pragma unroll
        for (int off = 32; off > 0; off >>= 1) p += __shfl_down(p, off);
        if (lane == 0) {
            cum += p + b;
            out[t * NB + n] = cum;
        }
    }
}

extern "C" void kernel_launch(void* const* d_in, const int* in_sizes, int n_in,
                              void* d_out, int out_size, void* d_ws, size_t ws_size,
                              hipStream_t stream) {
    (void)in_sizes; (void)n_in; (void)out_size;
    const float* x      = (const float*)d_in[0];
    const float* w_jeff = (const float*)d_in[1];
    const float* w_cc   = (const float*)d_in[2];
    const float* w_sf0  = (const float*)d_in[3];
    const float* W1     = (const float*)d_in[4];
    const float* w_sf1  = (const float*)d_in[5];
    const float* W2     = (const float*)d_in[6];
    const float* w_sf2  = (const float*)d_in[7];
    const float* W3     = (const float*)d_in[8];
    const float* w_sf3  = (const float*)d_in[9];
    const float* W_out  = (const float*)d_in[10];
    const float* b_out  = (const float*)d_in[11];
    float* out = (float*)d_out;

    const int M = T_STEPS * NB;                 // 2048
    // ws layout (floats):
    //   y7  : M*512              (front-end output / GEMM1 A)
    //   z1  : M*2048             (GEMM1 out; later reused for GEMM3 partials)
    //   z2p : ksplit2 * M*1024   (GEMM2 split-K partials; result in part 0)
    // GEMM3 partials (4 * M*512 = M*2048 floats) overlay z1 (dead by then).
    float* y7  = (float*)d_ws;
    float* z1  = y7 + (size_t)M * 512;
    float* z2p = z1 + (size_t)M * 2048;
    float* z3p = z1;                            // overlay

    // split-K=2 for GEMM2 needs 2 partial buffers; fall back if ws is short.
    size_t need2 = ((size_t)M * 512 + (size_t)M * 2048 + 2 * (size_t)M * 1024) * 4;
    const int ksplit2 = (ws_size >= need2) ? 2 : 1;

    // 1. front end -> y7
    front_kernel<<<NB * CC / 256, 256, 0, stream>>>(x, w_jeff, w_cc, w_sf0, w_sf1, y7);

    // 2. z1 = y7 @ W1^T : (2048,512)x(2048,512)^T -> (2048,2048); 512 blocks
    gemm_nt_db<128, 64, 16><<<dim3(2048 / 64, 2048 / 128, 1), 256, 0, stream>>>(
        y7, W1, z1, M, 2048, 512, 512);

    // 3. IF + filter(sf2) in place on z1
    if_filter_kernel<<<NB * 2048 / 256, 256, 0, stream>>>(z1, 0, 1, w_sf2, 2048);

    // 4. z2 = z1 @ W2^T -> (2048,1024), split-K; 512 blocks
    gemm_nt_db<128, 64, 16><<<dim3(1024 / 64, 2048 / 128, ksplit2), 256, 0, stream>>>(
        z1, W2, z2p, M, 1024, 2048, 2048 / ksplit2);

    // 5. sum partials + IF + filter(sf3) -> z2p[0]
    if_filter_kernel<<<NB * 1024 / 256, 256, 0, stream>>>(
        z2p, (size_t)M * 1024, ksplit2, w_sf3, 1024);

    // 6. z3 = z2 @ W3^T -> (2048,512), split-K=4; 512 blocks (overlays z1)
    gemm_nt_db<128, 64, 16><<<dim3(512 / 64, 2048 / 128, 4), 256, 0, stream>>>(
        z2p, W3, z3p, M, 512, 1024, 1024 / 4);

    // 7. sum partials + IF (raw spikes) -> z3p[0]
    if_filter_kernel<<<NB * 512 / 256, 256, 0, stream>>>(
        z3p, (size_t)M * 512, 4, nullptr, 512);

    // 8. final dot + bias + cumsum
    final_kernel<<<NB, 64, 0, stream>>>(z3p, W_out, b_out, out);
}

// Round 3
// 373.624 us; speedup vs baseline: 1.2341x; 1.2341x over previous
//
#include <hip/hip_runtime.h>
#include <math.h>

#define T_STEPS 32
#define NB 64      // batch
#define CC 512     // channels
#define AA 32      // cc_acc size

__device__ __forceinline__ float sig_decay(const float* wp) {
    // decay = 1 - sigmoid(w)
    return 1.0f - 1.0f / (1.0f + expf(-wp[0]));
}

// ---------------------------------------------------------------------------
// Front end: transpose + synapse(tau=2) + jeffress(2->32) + LIF(1.5) +
// synapse(sf0) + w_cc(32->1) + IF + synapse(sf1).  One thread per (n,c),
// loops t; all recurrent state in registers.  Writes y7 (T*N, 512).
// ---------------------------------------------------------------------------
__global__ __launch_bounds__(256) void front_kernel(
    const float* __restrict__ x, const float* __restrict__ w_jeff,
    const float* __restrict__ w_cc, const float* __restrict__ w_sf0,
    const float* __restrict__ w_sf1, float* __restrict__ y7)
{
    __shared__ float wj[2 * AA];
    __shared__ float wcc[AA];
    int tid = threadIdx.x;
    if (tid < 2 * AA) wj[tid] = w_jeff[tid];
    if (tid < AA) wcc[tid] = w_cc[tid];
    __syncthreads();

    int g = blockIdx.x * 256 + tid;     // n*CC + c
    int n = g >> 9;
    int c = g & (CC - 1);

    const float inv_lif = 1.0f / 1.5f;
    float d0 = sig_decay(w_sf0);
    float d1 = sig_decay(w_sf1);

    float s0 = 0.f, s1 = 0.f, v6 = 0.f, u1 = 0.f;
    float v[AA], u[AA];
#pragma unroll
    for (int a = 0; a < AA; a++) { v[a] = 0.f; u[a] = 0.f; }

    for (int t = 0; t < T_STEPS; t++) {
        const float* xp = x + (size_t)((t * NB + n) * 2) * CC + c;
        s0 = s0 * 0.5f + xp[0];     // synapse filter, tau=2 (decay 0.5)
        s1 = s1 * 0.5f + xp[CC];
        float acc = 0.f;
#pragma unroll
        for (int a = 0; a < AA; a++) {
            float z  = wj[2 * a] * s0 + wj[2 * a + 1] * s1;
            float vv = v[a] + (z - v[a]) * inv_lif;   // LIF decay_input
            bool  sp = vv >= 1.0f;
            v[a] = sp ? 0.0f : vv;                    // hard reset
            float uu = u[a] * d0 + (sp ? 1.0f : 0.0f);
            u[a] = uu;
            acc += wcc[a] * uu;
        }
        v6 += acc;                                    // IFNode
        bool sp6 = v6 >= 1.0f;
        v6 = sp6 ? 0.0f : v6;
        u1 = u1 * d1 + (sp6 ? 1.0f : 0.0f);           // sf1 filter
        y7[(size_t)(t * NB + n) * CC + c] = u1;
    }
}

// ---------------------------------------------------------------------------
// IF (+ optional synapse filter) over the (deterministic, in-order) sum of
// `nparts` split-K partial buffers.  Result written in place into part 0.
// One thread per (n,f), loop t.  w_sf == nullptr -> emit raw spikes.
// ---------------------------------------------------------------------------
__global__ __launch_bounds__(256) void if_filter_kernel(
    float* __restrict__ buf, size_t partStride, int nparts,
    const float* __restrict__ w_sf, int F)
{
    int tid = blockIdx.x * 256 + threadIdx.x;   // n*F + f
    const int NF = NB * F;
    bool  filt = (w_sf != nullptr);
    float d = filt ? sig_decay(w_sf) : 0.0f;
    float v = 0.f, u = 0.f;
    for (int t = 0; t < T_STEPS; t++) {
        size_t off = (size_t)t * NF + tid;
        float zt = buf[off];
        for (int p = 1; p < nparts; p++) zt += buf[p * partStride + off];
        v += zt;
        bool sp = v >= 1.0f;
        v = sp ? 0.0f : v;
        float s = sp ? 1.0f : 0.0f;
        if (filt) { u = u * d + s; buf[off] = u; }
        else      { buf[off] = s; }
    }
}

// ---------------------------------------------------------------------------
// C = A * B^T, split-K.  A: (M,K) row-major, B: (N,K) row-major.
// Partial for split s goes to C + s*M*N over K range [s*K_per, (s+1)*K_per).
// 64x64 tile, BK=32, 256 threads as 16x16, 4x4 micro-tile.
// Single-buffered LDS (low VGPR -> many co-resident blocks hide barriers).
// ---------------------------------------------------------------------------
__global__ __launch_bounds__(256) void gemm_nt(
    const float* __restrict__ A, const float* __restrict__ B,
    float* __restrict__ C, int M, int N, int K_total, int K_per)
{
    constexpr int BM = 64, BN = 64, BK = 32;
    __shared__ float As[BK][BM + 4];   // transposed: As[kk][row], row-stride 68
    __shared__ float Bs[BK][BN + 4];

    const int tid = threadIdx.x;
    const int tx  = tid & 15;        // col group (4 cols each)
    const int ty  = tid >> 4;        // row group (4 rows each)
    const int bm  = blockIdx.y * BM;
    const int bn  = blockIdx.x * BN;
    const int s   = blockIdx.z;
    const int kbeg = s * K_per;

    float acc[4][4];
#pragma unroll
    for (int i = 0; i < 4; i++)
#pragma unroll
        for (int j = 0; j < 4; j++) acc[i][j] = 0.f;

    // per K-tile: each thread loads 2 float4 of A and 2 of B
    // idx = i*256+tid; row = idx>>3 (8 k-quads per row), kq = idx&7
    const int lrow = tid >> 3;
    const int lkq  = tid & 7;

    for (int kt = 0; kt < K_per; kt += BK) {
        int k0 = kbeg + kt;
        __syncthreads();
#pragma unroll
        for (int i = 0; i < 2; i++) {
            int row = lrow + i * 32;
            float4 av = *(const float4*)(A + (size_t)(bm + row) * K_total + k0 + lkq * 4);
            As[lkq * 4 + 0][row] = av.x;
            As[lkq * 4 + 1][row] = av.y;
            As[lkq * 4 + 2][row] = av.z;
            As[lkq * 4 + 3][row] = av.w;
            float4 bv = *(const float4*)(B + (size_t)(bn + row) * K_total + k0 + lkq * 4);
            Bs[lkq * 4 + 0][row] = bv.x;
            Bs[lkq * 4 + 1][row] = bv.y;
            Bs[lkq * 4 + 2][row] = bv.z;
            Bs[lkq * 4 + 3][row] = bv.w;
        }
        __syncthreads();
#pragma unroll
        for (int kk = 0; kk < BK; kk++) {
            float4 a0 = *(const float4*)&As[kk][ty * 4];
            float4 b0 = *(const float4*)&Bs[kk][tx * 4];
            float ar[4] = {a0.x, a0.y, a0.z, a0.w};
            float br[4] = {b0.x, b0.y, b0.z, b0.w};
#pragma unroll
            for (int i = 0; i < 4; i++)
#pragma unroll
                for (int j = 0; j < 4; j++) acc[i][j] += ar[i] * br[j];
        }
    }

    float* Cp = C + (size_t)s * M * N;
#pragma unroll
    for (int i = 0; i < 4; i++) {
        float4 o;
        o.x = acc[i][0]; o.y = acc[i][1]; o.z = acc[i][2]; o.w = acc[i][3];
        *(float4*)(Cp + (size_t)(bm + ty * 4 + i) * N + bn + tx * 4) = o;
    }
}

// ---------------------------------------------------------------------------
// Final: out[t,n] = cumsum_t( dot(y15[t,n,:512], W_out) + b ).
// One wave (64 threads) per n.
// ---------------------------------------------------------------------------
__global__ __launch_bounds__(64) void final_kernel(
    const float* __restrict__ y15, const float* __restrict__ W_out,
    const float* __restrict__ b_out, float* __restrict__ out)
{
    int n = blockIdx.x;
    int lane = threadIdx.x;
    float w[8];
#pragma unroll
    for (int j = 0; j < 8; j++) w[j] = W_out[lane + j * 64];
    float b = b_out[0];
    float cum = 0.f;
    for (int t = 0; t < T_STEPS; t++) {
        const float* yp = y15 + (size_t)(t * NB + n) * 512;
        float p = 0.f;
#pragma unroll
        for (int j = 0; j < 8; j++) p += yp[lane + j * 64] * w[j];
#pragma unroll
        for (int off = 32; off > 0; off >>= 1) p += __shfl_down(p, off);
        if (lane == 0) {
            cum += p + b;
            out[t * NB + n] = cum;
        }
    }
}

extern "C" void kernel_launch(void* const* d_in, const int* in_sizes, int n_in,
                              void* d_out, int out_size, void* d_ws, size_t ws_size,
                              hipStream_t stream) {
    (void)in_sizes; (void)n_in; (void)out_size;
    const float* x      = (const float*)d_in[0];
    const float* w_jeff = (const float*)d_in[1];
    const float* w_cc   = (const float*)d_in[2];
    const float* w_sf0  = (const float*)d_in[3];
    const float* W1     = (const float*)d_in[4];
    const float* w_sf1  = (const float*)d_in[5];
    const float* W2     = (const float*)d_in[6];
    const float* w_sf2  = (const float*)d_in[7];
    const float* W3     = (const float*)d_in[8];
    const float* w_sf3  = (const float*)d_in[9];
    const float* W_out  = (const float*)d_in[10];
    const float* b_out  = (const float*)d_in[11];
    float* out = (float*)d_out;

    const int M = T_STEPS * NB;                 // 2048
    // ws layout (floats):
    //   y7  : M*512              (front-end output / GEMM1 A)
    //   z1  : M*2048             (GEMM1 out; later reused for GEMM3 partials)
    //   z2p : ksplit2 * M*1024   (GEMM2 split-K partials; result in part 0)
    // GEMM3 partials (4 * M*512 = M*2048 floats) overlay z1 (dead by then).
    float* y7  = (float*)d_ws;
    float* z1  = y7 + (size_t)M * 512;
    float* z2p = z1 + (size_t)M * 2048;
    float* z3p = z1;                            // overlay

    size_t need2 = ((size_t)M * 512 + (size_t)M * 2048 + 2 * (size_t)M * 1024) * 4;
    const int ksplit2 = (ws_size >= need2) ? 2 : 1;

    // 1. front end -> y7
    front_kernel<<<NB * CC / 256, 256, 0, stream>>>(x, w_jeff, w_cc, w_sf0, w_sf1, y7);

    // 2. z1 = y7 @ W1^T : (2048,512)x(2048,512)^T -> (2048,2048); 1024 blocks
    gemm_nt<<<dim3(2048 / 64, 2048 / 64, 1), 256, 0, stream>>>(
        y7, W1, z1, M, 2048, 512, 512);

    // 3. IF + filter(sf2) in place on z1
    if_filter_kernel<<<NB * 2048 / 256, 256, 0, stream>>>(z1, 0, 1, w_sf2, 2048);

    // 4. z2 = z1 @ W2^T -> (2048,1024), split-K=2; 1024 blocks
    gemm_nt<<<dim3(1024 / 64, 2048 / 64, ksplit2), 256, 0, stream>>>(
        z1, W2, z2p, M, 1024, 2048, 2048 / ksplit2);

    // 5. sum partials + IF + filter(sf3) -> z2p[0]
    if_filter_kernel<<<NB * 1024 / 256, 256, 0, stream>>>(
        z2p, (size_t)M * 1024, ksplit2, w_sf3, 1024);

    // 6. z3 = z2 @ W3^T -> (2048,512), split-K=4; 1024 blocks (overlays z1)
    gemm_nt<<<dim3(512 / 64, 2048 / 64, 4), 256, 0, stream>>>(
        z2p, W3, z3p, M, 512, 1024, 1024 / 4);

    // 7. sum partials + IF (raw spikes) -> z3p[0]
    if_filter_kernel<<<NB * 512 / 256, 256, 0, stream>>>(
        z3p, (size_t)M * 512, 4, nullptr, 512);

    // 8. final dot + bias + cumsum
    final_kernel<<<NB, 64, 0, stream>>>(z3p, W_out, b_out, out);
}